// Round 18
// baseline (122.951 us; speedup 1.0000x reference)
//
#include <hip/hip_runtime.h>
#include <hip/hip_bf16.h>

// transformAttention fused MFMA kernel (round 18)
// r17 (122.9us, verified): hoisted weights under (256,3), VGPR 84, no spills.
// VALU is the tallest pipe (41%); biggest discrete block = PV's packed-bf16
// unpack (288 shift/and per wave) + non-ideal PV read pattern.
// Round 18 = r17 + f32 pbuf: scatter unpacks pw ONCE (64 ops) and writes f32
// via ds_write_b128 into [w][ni][q][hslot^q][p<12] (q-stride 384B, h XOR) ->
// PV = 3x ds_read_b128 + 12 direct fmaf per (q,ni), provably bank-clean.
// pbuf spans ALL 36864B LDS (v-slab dead after vv reads, all waves pre-B2);
// tbuf overlays per-wave pbuf after PV (extra WAR fence). All else r17.
// LDS map (36864 B):
//   pre-B2:  [0,12288) q | [12288,24576) k | [24576,36864) v (vv->regs at B1)
//   post-B2: per-wave 9216B pbuf at w*9216  -> tbuf (2x1536B) overlay

typedef __attribute__((ext_vector_type(8))) short bf16x8;
typedef __attribute__((ext_vector_type(4))) float f32x4;

constexpr int Bb = 16, Ss = 12, Nn = 2048, Dd = 64;
constexpr float EXPK = 0.51011687f;   // (1/sqrt(8)) * log2(e)
constexpr int KOFS = 12288, VOFS = 24576, LDSZ = 36864;

#define MFMA16(A, B, C) __builtin_amdgcn_mfma_f32_16x16x32_bf16((A), (B), (C), 0, 0, 0)

__device__ __forceinline__ short f2bf(float f) {
    __hip_bfloat16 h = __float2bfloat16(f);
    short s; __builtin_memcpy(&s, &h, 2); return s;
}
__device__ __forceinline__ float bitf(unsigned u) {
    float f; __builtin_memcpy(&f, &u, 4); return f;
}
__device__ __forceinline__ float bf2f(unsigned short v) {
    return bitf(((unsigned)v) << 16);
}
__device__ __forceinline__ unsigned cvtpk(float lo, float hi) {
    unsigned r;
    asm("v_cvt_pk_bf16_f32 %0, %1, %2" : "=v"(r) : "v"(lo), "v"(hi));
    return r;
}
__device__ __forceinline__ void lds_fence() {
    asm volatile("s_waitcnt lgkmcnt(0)" ::: "memory");
    __builtin_amdgcn_sched_barrier(0);
}
// q/k/v slab byte offset (single source of truth for the swizzle)
__device__ __forceinline__ int qkOfs(int t, int s, int n, int d) {
    return t * KOFS + s * 1024 + n * 128 + ((2 * d) ^ (((s & 7) ^ (n & 7)) << 4));
}
// f32 pbuf: per-wave 9216B at w*9216; [ni][q][hslot][p]: ni*4608 + q*384 +
// (h^(q&7))*48 + p*4   (q-stride 96 dwords == 0 mod 32; h-slot XOR spreads)
__device__ __forceinline__ int pOfs(int w, int ni, int q, int hslot, int p) {
    return w * 9216 + ni * 4608 + q * 384 + hslot * 48 + p * 4;
}
// tbuf overlay on per-wave pbuf: 2 x 1536B
__device__ __forceinline__ int vtOfs(int w, int ni, int row, int d) {
    return w * 9216 + ni * 1536 + row * 128 + ((2 * d) ^ ((row & 7) << 4));
}

// prep: d_ws <- bf16 W^T for Wff, W1, W2: wt[m][r*64+c] = W[c][r]
__global__ void prep_w(const float* __restrict__ Wff, const float* __restrict__ W1,
                       const float* __restrict__ W2, unsigned short* __restrict__ wt) {
    int idx = blockIdx.x * 256 + threadIdx.x;
    if (idx >= 3 * 4096) return;
    int m = idx >> 12, rc = idx & 4095, r = rc >> 6, c = rc & 63;
    const float* W = (m == 0) ? Wff : (m == 1) ? W1 : W2;
    unsigned short u; short s = f2bf(W[c * 64 + r]);
    __builtin_memcpy(&u, &s, 2);
    wt[idx] = u;
}

__global__ __launch_bounds__(256, 3)
void ta_mfma16(const float* __restrict__ x,
               const float* __restrict__ steP,
               const float* __restrict__ steQ,
               const float* __restrict__ bff, const float* __restrict__ b1,
               const float* __restrict__ b2,
               const unsigned short* __restrict__ wt,
               float* __restrict__ out)
{
    alignas(16) __shared__ char smem[LDSZ];

    const int tid = threadIdx.x;
    const int w   = tid >> 6;      // 0..3
    const int l   = tid & 63;
    const int l15 = l & 15;
    const int l4  = l >> 4;
    const int b   = blockIdx.y;
    const int n0  = blockIdx.x * 8;

    // ---- hoisted loads: W_ff frags, W1 frags, all biases ----
    bf16x8 wf[4][2], w1f[4][2];
    float bfv[4], b1v[4], b2v[4];
    #pragma unroll
    for (int nt = 0; nt < 4; ++nt) {
        bfv[nt] = bff[nt * 16 + l15];
        b1v[nt] = b1[nt * 16 + l15];
        b2v[nt] = b2[nt * 16 + l15];
        #pragma unroll
        for (int kc = 0; kc < 2; ++kc) {
            wf[nt][kc]  = *(const bf16x8*)(wt +        (nt * 16 + l15) * 64 + kc * 32 + l4 * 8);
            w1f[nt][kc] = *(const bf16x8*)(wt + 4096 + (nt * 16 + l15) * 64 + kc * 32 + l4 * 8);
        }
    }

    // ---- phase 1: projections, 18 jobs = 3 tensors x 6 s-pairs, 4 waves ----
    const int sA = l15 >> 3, nA = l15 & 7;
    for (int job = w; job < 18; job += 4) {
        const int t = job / 6, s0 = (job % 6) * 2;
        const float* base = (t == 0) ? steQ : (t == 1) ? steP : x;
        const float* rp = base + ((size_t)(b * Ss + s0 + sA) * Nn + n0 + nA) * Dd + l4 * 8;

        bf16x8 a[2];
        #pragma unroll
        for (int kc = 0; kc < 2; ++kc) {
            float4 p0 = *(const float4*)(rp + kc * 32);
            float4 p1 = *(const float4*)(rp + kc * 32 + 4);
            union { unsigned u[4]; bf16x8 v; } cv;
            cv.u[0] = cvtpk(p0.x, p0.y); cv.u[1] = cvtpk(p0.z, p0.w);
            cv.u[2] = cvtpk(p1.x, p1.y); cv.u[3] = cvtpk(p1.z, p1.w);
            a[kc] = cv.v;
        }
        #pragma unroll
        for (int nt = 0; nt < 4; ++nt) {
            f32x4 acc = { bfv[nt], bfv[nt], bfv[nt], bfv[nt] };
            acc = MFMA16(a[0], wf[nt][0], acc);
            acc = MFMA16(a[1], wf[nt][1], acc);
            const int d = nt * 16 + l15;
            #pragma unroll
            for (int q = 0; q < 4; ++q) {
                const int r = l4 * 4 + q, s = s0 + (r >> 3), nn = r & 7;
                *(short*)(smem + qkOfs(t, s, nn, d)) = f2bf(acc[q]);
            }
        }
    }
    __syncthreads();   // B1: q,k,v ready (hoisted vmem also drained here)

    // ---- v rows into regs (lane = d), both ni (before B2: v-slab dies) ----
    float vv[2][12];
    #pragma unroll
    for (int ni = 0; ni < 2; ++ni)
        #pragma unroll
        for (int s = 0; s < 12; ++s)
            vv[ni][s] = bf2f(*(const unsigned short*)(smem + qkOfs(2, s, w * 2 + ni, l)));

    // ---- phase 2a: per-head QK^T (swapped) + softmax; both ni interleaved ----
    unsigned pw[2][8][2];
    #pragma unroll
    for (int h = 0; h < 8; ++h) {
        #pragma unroll
        for (int ni = 0; ni < 2; ++ni) {
            const int n = w * 2 + ni;
            union { unsigned u[4]; bf16x8 v; } akk;
            akk.v = *(const bf16x8*)(smem + qkOfs(1, l15, n, h * 8));
            bf16x8 aq = *(const bf16x8*)(smem + qkOfs(0, l15, n, h * 8));
            if (l4 != 0) { akk.u[0] = 0; akk.u[1] = 0; akk.u[2] = 0; akk.u[3] = 0; }
            f32x4 c = { 0.f, 0.f, 0.f, 0.f };
            c = MFMA16(akk.v, aq, c);     // S^T: row p = l4*4+reg, col q = l15
            float e[4];
            #pragma unroll
            for (int i = 0; i < 4; ++i) {
                float v = __builtin_amdgcn_exp2f(c[i] * EXPK);
                e[i] = (l4 == 3) ? 0.f : v;     // zero p >= 12 / garbage rows
            }
            float ssum = (e[0] + e[1]) + (e[2] + e[3]);
            ssum += __shfl_xor(ssum, 16);
            ssum += __shfl_xor(ssum, 32);
            float inv;
            asm("v_rcp_f32 %0, %1" : "=v"(inv) : "v"(ssum));
            pw[ni][h][0] = cvtpk(e[0] * inv, e[1] * inv);
            pw[ni][h][1] = cvtpk(e[2] * inv, e[3] * inv);
        }
    }
    __syncthreads();   // B2: all slabs dead -> per-wave f32 pbuf (all of LDS)

    // ---- phase 2b: f32 pbuf scatter (one-time unpack) + direct-fma PV ----
    #pragma unroll
    for (int ni = 0; ni < 2; ++ni) {
        if (l15 < 12 && l4 < 3) {
            #pragma unroll
            for (int h = 0; h < 8; ++h) {
                f32x4 pv4;
                pv4[0] = bitf(pw[ni][h][0] << 16);
                pv4[1] = bitf(pw[ni][h][0] & 0xFFFF0000u);
                pv4[2] = bitf(pw[ni][h][1] << 16);
                pv4[3] = bitf(pw[ni][h][1] & 0xFFFF0000u);
                // p = l4*4 + i; row q = l15; h-slot = h ^ (q&7)
                *(f32x4*)(smem + pOfs(w, ni, l15, h ^ (l15 & 7), l4 * 4)) = pv4;
            }
        }
    }
    lds_fence();   // F1: pbuf visible before PV reads

    float oacc[2][12];
    const int hme = l >> 3;   // lane's head = d>>3
    #pragma unroll
    for (int q = 0; q < 12; ++q) {
        const int hslot = hme ^ (q & 7);
        #pragma unroll
        for (int ni = 0; ni < 2; ++ni) {
            const char* qp = smem + pOfs(w, ni, q, hslot, 0);
            f32x4 p0 = *(const f32x4*)(qp);
            f32x4 p1 = *(const f32x4*)(qp + 16);
            f32x4 p2 = *(const f32x4*)(qp + 32);
            float a = 0.f;
            #pragma unroll
            for (int i = 0; i < 4; ++i) a = fmaf(p0[i], vv[ni][i],     a);
            #pragma unroll
            for (int i = 0; i < 4; ++i) a = fmaf(p1[i], vv[ni][4 + i], a);
            #pragma unroll
            for (int i = 0; i < 4; ++i) a = fmaf(p2[i], vv[ni][8 + i], a);
            oacc[ni][q] = a;
        }
    }
    lds_fence();   // F1b (WAR): PV reads retired before tbuf overlays pbuf

    // ---- issue W2 frag loads here: hidden under tbuf writes + F2 + FFN1 ----
    bf16x8 w2f[4][2];
    #pragma unroll
    for (int nt = 0; nt < 4; ++nt)
        #pragma unroll
        for (int kc = 0; kc < 2; ++kc)
            w2f[nt][kc] = *(const bf16x8*)(wt + 8192 + (nt * 16 + l15) * 64 + kc * 32 + l4 * 8);

    // ---- tbuf writes (overlay per-wave pbuf region) ----
    #pragma unroll
    for (int ni = 0; ni < 2; ++ni)
        #pragma unroll
        for (int q = 0; q < 12; ++q)
            *(short*)(smem + vtOfs(w, ni, q, l)) = f2bf(oacc[ni][q]);
    lds_fence();   // F2: tbuf visible before FFN1 reads

    const int l15c = (l15 < 12) ? l15 : 0;   // clamp B rows 12..15 (C cols discarded)

    // ---- phase 3: FFN, wave-private, both ni ----
    #pragma unroll
    for (int ni = 0; ni < 2; ++ni) {
        bf16x8 a[2];
        #pragma unroll
        for (int kc = 0; kc < 2; ++kc)
            a[kc] = *(const bf16x8*)(smem + vtOfs(w, ni, l15c, kc * 32 + l4 * 8));
        #pragma unroll
        for (int nt = 0; nt < 4; ++nt) {
            f32x4 acc = { b1v[nt], b1v[nt], b1v[nt], b1v[nt] };
            acc = MFMA16(a[0], w1f[nt][0], acc);
            acc = MFMA16(a[1], w1f[nt][1], acc);
            #pragma unroll
            for (int reg = 0; reg < 4; ++reg) {
                const int rt = l4 * 4 + reg;
                if (rt < 12)
                    *(short*)(smem + vtOfs(w, ni, rt, nt * 16 + l15)) =
                        f2bf(fmaxf(acc[reg], 0.f));
            }
        }
    }
    lds_fence();   // F3: hid visible before FFN2 reads
    #pragma unroll
    for (int ni = 0; ni < 2; ++ni) {
        bf16x8 a[2];
        #pragma unroll
        for (int kc = 0; kc < 2; ++kc)
            a[kc] = *(const bf16x8*)(smem + vtOfs(w, ni, l15c, kc * 32 + l4 * 8));
        #pragma unroll
        for (int nt = 0; nt < 4; ++nt) {
            f32x4 acc = { b2v[nt], b2v[nt], b2v[nt], b2v[nt] };
            acc = MFMA16(a[0], w2f[nt][0], acc);
            acc = MFMA16(a[1], w2f[nt][1], acc);
            #pragma unroll
            for (int reg = 0; reg < 4; ++reg) {
                const int q = l4 * 4 + reg;
                if (q < 12)
                    out[((size_t)(b * Ss + q) * Nn + n0 + w * 2 + ni) * Dd + nt * 16 + l15] = acc[reg];
            }
        }
    }
}

extern "C" void kernel_launch(void* const* d_in, const int* in_sizes, int n_in,
                              void* d_out, int out_size, void* d_ws, size_t ws_size,
                              hipStream_t stream) {
    const float* x    = (const float*)d_in[0];
    const float* steP = (const float*)d_in[1];
    const float* steQ = (const float*)d_in[2];
    const float* Wff  = (const float*)d_in[3];
    const float* bff  = (const float*)d_in[4];
    const float* W1   = (const float*)d_in[5];
    const float* b1   = (const float*)d_in[6];
    const float* W2   = (const float*)d_in[7];
    const float* b2   = (const float*)d_in[8];
    float* out = (float*)d_out;
    unsigned short* wtp = (unsigned short*)d_ws;

    prep_w<<<48, 256, 0, stream>>>(Wff, W1, W2, wtp);
    dim3 grid(Nn / 8, Bb);
    ta_mfma16<<<grid, 256, 0, stream>>>(x, steP, steQ, bff, b1, b2, wtp, out);
}